// Round 8
// baseline (433.649 us; speedup 1.0000x reference)
//
#include <hip/hip_runtime.h>
#include <hip/hip_fp16.h>
#include <math.h>

#define N_NODES 50000
#define F_IN 32
#define DEG 32
#define BATCH 2048
#define GRID_BLKS 1024

typedef _Float16 half8 __attribute__((ext_vector_type(8)));
typedef _Float16 half2v __attribute__((ext_vector_type(2)));
typedef int int4v __attribute__((ext_vector_type(4)));
typedef unsigned int uint2v __attribute__((ext_vector_type(2)));
typedef float f32x2 __attribute__((ext_vector_type(2)));

__device__ __forceinline__ void softmax3(float a0, float a1, float a2,
                                         float& w0, float& w1, float& w2) {
    float m = fmaxf(a0, fmaxf(a1, a2));
    float e0 = __expf(a0 - m), e1 = __expf(a1 - m), e2 = __expf(a2 - m);
    float s = 1.f / (e0 + e1 + e2);
    w0 = e0 * s; w1 = e1 * s; w2 = e2 * s;
}

__device__ __forceinline__ f32x2 shfl_xor_f2(f32x2 v, int m) {
    v.x = __shfl_xor(v.x, m, 64);
    v.y = __shfl_xor(v.y, m, 64);
    return v;
}

// Manual grid barrier: all GRID_BLKS blocks are co-resident
// (launch_bounds(256,4) => VGPR<=128 => 4 blocks/CU x 256 CU = 1024).
// Device-scope fence before arrival (release) and after pass (acquire)
// handles cross-XCD L2 non-coherence. cnt zeroed by hipMemsetAsync per call.
__device__ __forceinline__ void grid_barrier(int* cnt) {
    __syncthreads();
    if (threadIdx.x == 0) {
        __threadfence();  // release: make this block's writes device-visible
        __hip_atomic_fetch_add(cnt, 1, __ATOMIC_RELAXED, __HIP_MEMORY_SCOPE_AGENT);
        while (__hip_atomic_load(cnt, __ATOMIC_ACQUIRE, __HIP_MEMORY_SCOPE_AGENT)
               < GRID_BLKS) {
            __builtin_amdgcn_s_sleep(2);
        }
        __threadfence();  // acquire: invalidate stale local caches
    }
    __syncthreads();
}

__global__ __launch_bounds__(256, 4) void fused_kernel(
        const int* __restrict__ nodes,
        const float* __restrict__ feat,
        const int* __restrict__ adj,
        const float* __restrict__ prior,
        const float* __restrict__ w_mlp,
        const float* __restrict__ b_mlp,
        const float* __restrict__ alpha1,
        const float* __restrict__ alpha2,
        const float* __restrict__ w_d2,
        const float* __restrict__ b_d2,
        const float* __restrict__ w_d1,
        const float* __restrict__ b_d1,
        float* __restrict__ sw1,
        float* __restrict__ sw2,
        _Float16* __restrict__ h0h,
        unsigned char* __restrict__ h0q,
        _Float16* __restrict__ i1h,
        unsigned char* __restrict__ i1q,
        int* __restrict__ barrier_cnt,
        float* __restrict__ out) {
    __shared__ alignas(16) char smraw[9216];
    int tid = threadIdx.x;
    int bid = blockIdx.x;

    // ============ Phase 1: softmax tables + h0 = relu(feat@w_mlp+b) ============
    {
        float* wl = (float*)smraw;             // 2048 floats
        float* fl = (float*)(smraw + 8192);    // 256 floats
        if (bid == 0) {
            for (int q = tid; q < 384; q += 256) {
                const float* src = (q < 128) ? (alpha1 + q * 3) : (alpha2 + (q - 128) * 3);
                float* dst = (q < 128) ? (sw1 + q * 3) : (sw2 + (q - 128) * 3);
                float w0, w1, w2;
                softmax3(src[0], src[1], src[2], w0, w1, w2);
                dst[0] = w0; dst[1] = w1; dst[2] = w2;
            }
        }
        for (int i = tid; i < F_IN * 64; i += 256) wl[i] = w_mlp[i];
        int local = tid >> 5;        // node 0..7
        int f2 = (tid & 31) * 2;     // feature pair
        float b0 = b_mlp[f2], b1 = b_mlp[f2 + 1];
        const int noct = N_NODES / 8;  // 6250
        for (int q = bid; q < noct; q += GRID_BLKS) {
            int n0 = q * 8;
            __syncthreads();
            fl[tid] = __builtin_nontemporal_load(feat + (size_t)n0 * F_IN + tid);
            __syncthreads();
            float a0 = b0, a1 = b1;
#pragma unroll
            for (int k = 0; k < F_IN; ++k) {
                float v = fl[local * F_IN + k];
                a0 = fmaf(v, wl[k * 64 + f2], a0);
                a1 = fmaf(v, wl[k * 64 + f2 + 1], a1);
            }
            a0 = fmaxf(a0, 0.f);
            a1 = fmaxf(a1, 0.f);
            int n = n0 + local;
            half2v hv = {(_Float16)a0, (_Float16)a1};
            *reinterpret_cast<half2v*>(h0h + (size_t)n * 64 + f2) = hv;
            unsigned pk = __builtin_amdgcn_cvt_pk_fp8_f32(a0, a1, 0u, false);
            *reinterpret_cast<unsigned short*>(h0q + (size_t)n * 64 + f2) =
                (unsigned short)pk;
        }
    }
    grid_barrier(barrier_cnt);

    // ============ Phase 2: layer-1 InterAgg, 8-node tiles, 2 nodes/wave ============
    {
        int* nb = (int*)smraw;                 // 8 * 100 ints
        float* swl = (float*)(smraw + 3200);   // 384 floats
        if (tid < 96)
            reinterpret_cast<float4*>(swl)[tid] = reinterpret_cast<const float4*>(sw1)[tid];
        int w = tid >> 6, j = tid & 63;
        int m = w * 2 + (j >> 5);    // node local 0..7
        int e = j & 7;               // feature octet
        int rg = (j >> 3) & 3;       // row group 0..3 (8 rows each)
        const int* nbrow = nb + m * 100;
        const unsigned char* qb = h0q + 8 * e;
        const int ntiles = N_NODES / 8;  // 6250
        for (int tile = bid; tile < ntiles; tile += GRID_BLKS) {
            int n0 = tile * 8;
            __syncthreads();
            if (tid < 192) {
                int r = tid >> 6;
                int mm = (tid >> 3) & 7;
                int d4 = (tid & 7) * 4;
                int4v v = __builtin_nontemporal_load(reinterpret_cast<const int4v*>(
                        adj + ((size_t)r * N_NODES + (n0 + mm)) * DEG + d4));
                *reinterpret_cast<int4v*>(&nb[mm * 100 + r * 32 + d4]) = v;
            }
            __syncthreads();
            f32x2 acc0[4] = {}, acc1[4] = {}, acc2[4] = {};
#pragma unroll
            for (int t = 0; t < 8; ++t) {
                uint2v d = *reinterpret_cast<const uint2v*>(
                    qb + (size_t)((unsigned)nbrow[rg * 8 + t] * 64u));
                acc0[0] += __builtin_amdgcn_cvt_pk_f32_fp8(d.x, false);
                acc0[1] += __builtin_amdgcn_cvt_pk_f32_fp8(d.x, true);
                acc0[2] += __builtin_amdgcn_cvt_pk_f32_fp8(d.y, false);
                acc0[3] += __builtin_amdgcn_cvt_pk_f32_fp8(d.y, true);
            }
#pragma unroll
            for (int t = 0; t < 8; ++t) {
                uint2v d = *reinterpret_cast<const uint2v*>(
                    qb + (size_t)((unsigned)nbrow[32 + rg * 8 + t] * 64u));
                acc1[0] += __builtin_amdgcn_cvt_pk_f32_fp8(d.x, false);
                acc1[1] += __builtin_amdgcn_cvt_pk_f32_fp8(d.x, true);
                acc1[2] += __builtin_amdgcn_cvt_pk_f32_fp8(d.y, false);
                acc1[3] += __builtin_amdgcn_cvt_pk_f32_fp8(d.y, true);
            }
#pragma unroll
            for (int t = 0; t < 8; ++t) {
                uint2v d = *reinterpret_cast<const uint2v*>(
                    qb + (size_t)((unsigned)nbrow[64 + rg * 8 + t] * 64u));
                acc2[0] += __builtin_amdgcn_cvt_pk_f32_fp8(d.x, false);
                acc2[1] += __builtin_amdgcn_cvt_pk_f32_fp8(d.x, true);
                acc2[2] += __builtin_amdgcn_cvt_pk_f32_fp8(d.y, false);
                acc2[3] += __builtin_amdgcn_cvt_pk_f32_fp8(d.y, true);
            }
            // combine the 4 row-groups (lane bits 3,4)
#pragma unroll
            for (int mm = 8; mm <= 16; mm <<= 1) {
#pragma unroll
                for (int q = 0; q < 4; ++q) {
                    acc0[q] += shfl_xor_f2(acc0[q], mm);
                    acc1[q] += shfl_xor_f2(acc1[q], mm);
                    acc2[q] += shfl_xor_f2(acc2[q], mm);
                }
            }
            if (rg < 2) {
                int n = n0 + m;
                const float* wt = swl + rg * 192 + 24 * e;
                float wv[24];
#pragma unroll
                for (int q = 0; q < 6; ++q) {
                    float4 tv = reinterpret_cast<const float4*>(wt)[q];
                    wv[4 * q] = tv.x; wv[4 * q + 1] = tv.y;
                    wv[4 * q + 2] = tv.z; wv[4 * q + 3] = tv.w;
                }
                const float inv = 1.f / 32.f;
                float o[8];
                half8 rh;
                if (rg == 0) {
#pragma unroll
                    for (int i = 0; i < 8; ++i) {
                        float a0 = acc0[i >> 1][i & 1] * inv;
                        float a1 = acc1[i >> 1][i & 1] * inv;
                        float a2 = acc2[i >> 1][i & 1] * inv;
                        o[i] = wv[3 * i] * a0 + wv[3 * i + 1] * a1 + wv[3 * i + 2] * a2;
                        rh[i] = (_Float16)o[i];
                    }
                } else {
                    half8 sv = *reinterpret_cast<const half8*>(h0h + (size_t)n * 64 + 8 * e);
#pragma unroll
                    for (int i = 0; i < 8; ++i) {
                        float a0 = acc0[i >> 1][i & 1] * inv;
                        float a1 = acc1[i >> 1][i & 1] * inv;
                        float a2 = acc2[i >> 1][i & 1] * inv;
                        float s = (float)sv[i];
                        o[i] = wv[3 * i] * (s - a0) + wv[3 * i + 1] * (s - a1) +
                               wv[3 * i + 2] * (s - a2);
                        rh[i] = (_Float16)o[i];
                    }
                }
                size_t base = (size_t)n * 128 + rg * 64 + 8 * e;
                __builtin_nontemporal_store(__builtin_bit_cast(int4v, rh),
                    reinterpret_cast<int4v*>(i1h + base));
                unsigned q0 = __builtin_amdgcn_cvt_pk_fp8_f32(o[0], o[1], 0u, false);
                q0 = __builtin_amdgcn_cvt_pk_fp8_f32(o[2], o[3], q0, true);
                unsigned q1 = __builtin_amdgcn_cvt_pk_fp8_f32(o[4], o[5], 0u, false);
                q1 = __builtin_amdgcn_cvt_pk_fp8_f32(o[6], o[7], q1, true);
                uint2v uq = {q0, q1};
                __builtin_nontemporal_store(uq, reinterpret_cast<uint2v*>(i1q + base));
            }
        }
    }
    grid_barrier(barrier_cnt + 32);

    // ============ Phase 3: layer-2 InterAgg (batch) + dense head ============
    if (bid < BATCH / 4) {
        int* nb3 = (int*)smraw;                 // 4*96 ints
        int* nid = (int*)(smraw + 1536);        // 4 ints
        float* swl3 = (float*)(smraw + 1552);   // 768 floats
        int b0 = bid * 4;
        if (tid < 4) nid[tid] = nodes[b0 + tid];
        if (tid >= 64 && tid < 256) {
            int q = tid - 64;
            reinterpret_cast<float4*>(swl3)[q] = reinterpret_cast<const float4*>(sw2)[q];
        }
        __syncthreads();
        for (int q = tid; q < 384; q += 256) {
            int local = q / 96, idx = q - local * 96;
            int r = idx >> 5, d = idx & 31;
            nb3[local * 96 + idx] = __builtin_nontemporal_load(
                adj + ((size_t)r * N_NODES + nid[local]) * DEG + d);
        }
        __syncthreads();
        int local = tid >> 6, j = tid & 63;
        int bb = b0 + local;
        int n = nid[local];
        int g = j >> 4, e = j & 15;
        int idxs[24];
#pragma unroll
        for (int t = 0; t < 24; ++t) idxs[t] = nb3[local * 96 + t * 4 + g];
        const unsigned char* qbase = i1q + 8 * e;
        f32x2 acc0[4] = {}, acc1[4] = {}, acc2[4] = {};
#pragma unroll
        for (int t = 0; t < 8; ++t) {
            uint2v d = *reinterpret_cast<const uint2v*>(
                qbase + (size_t)((unsigned)idxs[t] * 128u));
            acc0[0] += __builtin_amdgcn_cvt_pk_f32_fp8(d.x, false);
            acc0[1] += __builtin_amdgcn_cvt_pk_f32_fp8(d.x, true);
            acc0[2] += __builtin_amdgcn_cvt_pk_f32_fp8(d.y, false);
            acc0[3] += __builtin_amdgcn_cvt_pk_f32_fp8(d.y, true);
        }
#pragma unroll
        for (int t = 8; t < 16; ++t) {
            uint2v d = *reinterpret_cast<const uint2v*>(
                qbase + (size_t)((unsigned)idxs[t] * 128u));
            acc1[0] += __builtin_amdgcn_cvt_pk_f32_fp8(d.x, false);
            acc1[1] += __builtin_amdgcn_cvt_pk_f32_fp8(d.x, true);
            acc1[2] += __builtin_amdgcn_cvt_pk_f32_fp8(d.y, false);
            acc1[3] += __builtin_amdgcn_cvt_pk_f32_fp8(d.y, true);
        }
#pragma unroll
        for (int t = 16; t < 24; ++t) {
            uint2v d = *reinterpret_cast<const uint2v*>(
                qbase + (size_t)((unsigned)idxs[t] * 128u));
            acc2[0] += __builtin_amdgcn_cvt_pk_f32_fp8(d.x, false);
            acc2[1] += __builtin_amdgcn_cvt_pk_f32_fp8(d.x, true);
            acc2[2] += __builtin_amdgcn_cvt_pk_f32_fp8(d.y, false);
            acc2[3] += __builtin_amdgcn_cvt_pk_f32_fp8(d.y, true);
        }
#pragma unroll
        for (int mm = 16; mm <= 32; mm <<= 1) {
#pragma unroll
            for (int q = 0; q < 4; ++q) {
                acc0[q] += shfl_xor_f2(acc0[q], mm);
                acc1[q] += shfl_xor_f2(acc1[q], mm);
                acc2[q] += shfl_xor_f2(acc2[q], mm);
            }
        }
        const float inv = 1.f / 32.f;
        float p0 = 0.f, p1 = 0.f;
        if (g == 0) {
            half8 sv = *reinterpret_cast<const half8*>(i1h + (size_t)n * 128 + 8 * e);
            const float* wa = swl3 + 24 * e;
            const float* wb = swl3 + 384 + 24 * e;
#pragma unroll
            for (int i = 0; i < 8; ++i) {
                int f = 8 * e + i;
                float a0 = acc0[i >> 1][i & 1] * inv;
                float a1 = acc1[i >> 1][i & 1] * inv;
                float a2 = acc2[i >> 1][i & 1] * inv;
                float s = (float)sv[i];
                float i2a = wa[3 * i] * a0 + wa[3 * i + 1] * a1 + wa[3 * i + 2] * a2;
                float i2b = wb[3 * i] * (s - a0) + wb[3 * i + 1] * (s - a1) +
                            wb[3 * i + 2] * (s - a2);
                p0 += i2a * w_d2[(192 + f) * 2 + 0] + i2b * w_d2[(320 + f) * 2 + 0];
                p1 += i2a * w_d2[(192 + f) * 2 + 1] + i2b * w_d2[(320 + f) * 2 + 1];
            }
        } else if (g == 1) {
#pragma unroll
            for (int i = 0; i < 4; ++i) {
                int f = 4 * e + i;
                float s = (float)h0h[(size_t)n * 64 + f];
                p0 += s * w_d2[f * 2 + 0];
                p1 += s * w_d2[f * 2 + 1];
            }
        } else if (g == 2) {
            half8 sv = *reinterpret_cast<const half8*>(i1h + (size_t)n * 128 + 8 * e);
#pragma unroll
            for (int i = 0; i < 8; ++i) {
                int f = 8 * e + i;
                float s = (float)sv[i];
                p0 += s * w_d2[(64 + f) * 2 + 0];
                p1 += s * w_d2[(64 + f) * 2 + 1];
            }
        }
#pragma unroll
        for (int mm = 1; mm <= 32; mm <<= 1) {
            p0 += __shfl_xor(p0, mm, 64);
            p1 += __shfl_xor(p1, mm, 64);
        }
        if (j == 0) {
            float x0 = p0 + b_d2[0], x1 = p1 + b_d2[1];
            x0 = x0 > 0.f ? x0 : 0.3f * x0;
            x1 = x1 > 0.f ? x1 : 0.3f * x1;
            x0 += __logf(prior[0]);
            x1 += __logf(prior[1]);
            float z = x0 * w_d1[0] + x1 * w_d1[1] + b_d1[0];
            out[bb] = 1.f / (1.f + __expf(-z));
        }
    }
}

extern "C" void kernel_launch(void* const* d_in, const int* in_sizes, int n_in,
                              void* d_out, int out_size, void* d_ws, size_t ws_size,
                              hipStream_t stream) {
    const int*   nodes  = (const int*)d_in[0];
    const float* feat   = (const float*)d_in[1];
    const int*   adj    = (const int*)d_in[2];
    const float* prior  = (const float*)d_in[3];
    const float* w_mlp  = (const float*)d_in[4];
    const float* b_mlp  = (const float*)d_in[5];
    const float* alpha1 = (const float*)d_in[6];
    const float* alpha2 = (const float*)d_in[7];
    const float* w_d2   = (const float*)d_in[8];
    const float* b_d2   = (const float*)d_in[9];
    const float* w_d1   = (const float*)d_in[10];
    const float* b_d1   = (const float*)d_in[11];
    float* out = (float*)d_out;

    // ws: sw1(384f) | sw2(768f) | pad->8192 | h0h fp16 N*64 | i1h fp16 N*128 |
    //     h0q fp8 N*64 | i1q fp8 N*128 | ... | barrier counters @ +32MB
    float* sw1 = (float*)d_ws;
    float* sw2 = sw1 + 128 * 3;
    _Float16* h0h = (_Float16*)((char*)d_ws + 8192);
    _Float16* i1h = h0h + (size_t)N_NODES * 64;
    unsigned char* h0q = (unsigned char*)(i1h + (size_t)N_NODES * 128);
    unsigned char* i1q = h0q + (size_t)N_NODES * 64;
    int* barrier_cnt = (int*)((char*)d_ws + (size_t)32 * 1024 * 1024);

    hipMemsetAsync(barrier_cnt, 0, 256, stream);
    fused_kernel<<<GRID_BLKS, 256, 0, stream>>>(
        nodes, feat, adj, prior, w_mlp, b_mlp, alpha1, alpha2,
        w_d2, b_d2, w_d1, b_d1, sw1, sw2, h0h, h0q, i1h, i1q,
        barrier_cnt, out);
}

// Round 9
// 370.472 us; speedup vs baseline: 1.1705x; 1.1705x over previous
//
#include <hip/hip_runtime.h>
#include <hip/hip_fp16.h>
#include <math.h>

#define N_NODES 50000
#define F_IN 32
#define DEG 32
#define BATCH 2048
#define GRID_BLKS 1024

typedef _Float16 half8 __attribute__((ext_vector_type(8)));
typedef _Float16 half2v __attribute__((ext_vector_type(2)));
typedef int int4v __attribute__((ext_vector_type(4)));
typedef unsigned int uint2v __attribute__((ext_vector_type(2)));
typedef float f32x2 __attribute__((ext_vector_type(2)));

__device__ __forceinline__ void softmax3(float a0, float a1, float a2,
                                         float& w0, float& w1, float& w2) {
    float m = fmaxf(a0, fmaxf(a1, a2));
    float e0 = __expf(a0 - m), e1 = __expf(a1 - m), e2 = __expf(a2 - m);
    float s = 1.f / (e0 + e1 + e2);
    w0 = e0 * s; w1 = e1 * s; w2 = e2 * s;
}

__device__ __forceinline__ f32x2 shfl_xor_f2(f32x2 v, int m) {
    v.x = __shfl_xor(v.x, m, 64);
    v.y = __shfl_xor(v.y, m, 64);
    return v;
}

// Manual grid barrier. All GRID_BLKS blocks co-resident (launch_bounds(256,4)).
// CRITICAL: spin with RELAXED loads (no per-iteration cache invalidation —
// round-8's ACQUIRE-in-loop invalidated L2 chip-wide and cost 7x). One
// release fence+add on arrival, one acquire fence after exit.
__device__ __forceinline__ void grid_barrier(int* cnt) {
    __syncthreads();
    if (threadIdx.x == 0) {
        __threadfence();  // release: publish this block's writes
        __hip_atomic_fetch_add(cnt, 1, __ATOMIC_RELEASE, __HIP_MEMORY_SCOPE_AGENT);
        while (__hip_atomic_load(cnt, __ATOMIC_RELAXED, __HIP_MEMORY_SCOPE_AGENT)
               < GRID_BLKS) {
            __builtin_amdgcn_s_sleep(8);
        }
        __threadfence();  // acquire: invalidate stale caches ONCE
    }
    __syncthreads();
}

__global__ __launch_bounds__(256, 4) void fused_kernel(
        const int* __restrict__ nodes,
        const float* __restrict__ feat,
        const int* __restrict__ adj,
        const float* __restrict__ prior,
        const float* __restrict__ w_mlp,
        const float* __restrict__ b_mlp,
        const float* __restrict__ alpha1,
        const float* __restrict__ alpha2,
        const float* __restrict__ w_d2,
        const float* __restrict__ b_d2,
        const float* __restrict__ w_d1,
        const float* __restrict__ b_d1,
        float* __restrict__ sw1,
        float* __restrict__ sw2,
        _Float16* __restrict__ h0h,
        unsigned char* __restrict__ h0q,
        _Float16* __restrict__ i1h,
        unsigned char* __restrict__ i1q,
        int* __restrict__ barrier_cnt,
        float* __restrict__ out) {
    __shared__ alignas(16) char smraw[9216];
    int tid = threadIdx.x;
    int bid = blockIdx.x;

    // ============ Phase 1: softmax tables + h0 = relu(feat@w_mlp+b) ============
    {
        float* wl = (float*)smraw;             // 2048 floats
        float* fl = (float*)(smraw + 8192);    // 256 floats
        if (bid == 0) {
            for (int q = tid; q < 384; q += 256) {
                const float* src = (q < 128) ? (alpha1 + q * 3) : (alpha2 + (q - 128) * 3);
                float* dst = (q < 128) ? (sw1 + q * 3) : (sw2 + (q - 128) * 3);
                float w0, w1, w2;
                softmax3(src[0], src[1], src[2], w0, w1, w2);
                dst[0] = w0; dst[1] = w1; dst[2] = w2;
            }
        }
        for (int i = tid; i < F_IN * 64; i += 256) wl[i] = w_mlp[i];
        int local = tid >> 5;        // node 0..7
        int f2 = (tid & 31) * 2;     // feature pair
        float b0 = b_mlp[f2], b1 = b_mlp[f2 + 1];
        const int noct = N_NODES / 8;  // 6250
        for (int q = bid; q < noct; q += GRID_BLKS) {
            int n0 = q * 8;
            __syncthreads();
            fl[tid] = __builtin_nontemporal_load(feat + (size_t)n0 * F_IN + tid);
            __syncthreads();
            float a0 = b0, a1 = b1;
#pragma unroll
            for (int k = 0; k < F_IN; ++k) {
                float v = fl[local * F_IN + k];
                a0 = fmaf(v, wl[k * 64 + f2], a0);
                a1 = fmaf(v, wl[k * 64 + f2 + 1], a1);
            }
            a0 = fmaxf(a0, 0.f);
            a1 = fmaxf(a1, 0.f);
            int n = n0 + local;
            half2v hv = {(_Float16)a0, (_Float16)a1};
            *reinterpret_cast<half2v*>(h0h + (size_t)n * 64 + f2) = hv;
            unsigned pk = __builtin_amdgcn_cvt_pk_fp8_f32(a0, a1, 0u, false);
            *reinterpret_cast<unsigned short*>(h0q + (size_t)n * 64 + f2) =
                (unsigned short)pk;
        }
    }
    grid_barrier(barrier_cnt);

    // ============ Phase 2: layer-1 InterAgg, 8-node tiles, 2 nodes/wave ============
    {
        int* nb = (int*)smraw;                 // 8 * 100 ints
        float* swl = (float*)(smraw + 3200);   // 384 floats
        if (tid < 96)
            reinterpret_cast<float4*>(swl)[tid] = reinterpret_cast<const float4*>(sw1)[tid];
        int w = tid >> 6, j = tid & 63;
        int m = w * 2 + (j >> 5);    // node local 0..7
        int e = j & 7;               // feature octet
        int rg = (j >> 3) & 3;       // row group 0..3 (8 rows each)
        const int* nbrow = nb + m * 100;
        const unsigned char* qb = h0q + 8 * e;
        const int ntiles = N_NODES / 8;  // 6250
        for (int tile = bid; tile < ntiles; tile += GRID_BLKS) {
            int n0 = tile * 8;
            __syncthreads();
            if (tid < 192) {
                int r = tid >> 6;
                int mm = (tid >> 3) & 7;
                int d4 = (tid & 7) * 4;
                int4v v = __builtin_nontemporal_load(reinterpret_cast<const int4v*>(
                        adj + ((size_t)r * N_NODES + (n0 + mm)) * DEG + d4));
                *reinterpret_cast<int4v*>(&nb[mm * 100 + r * 32 + d4]) = v;
            }
            __syncthreads();
            f32x2 acc0[4] = {}, acc1[4] = {}, acc2[4] = {};
#pragma unroll
            for (int t = 0; t < 8; ++t) {
                uint2v d = *reinterpret_cast<const uint2v*>(
                    qb + (size_t)((unsigned)nbrow[rg * 8 + t] * 64u));
                acc0[0] += __builtin_amdgcn_cvt_pk_f32_fp8(d.x, false);
                acc0[1] += __builtin_amdgcn_cvt_pk_f32_fp8(d.x, true);
                acc0[2] += __builtin_amdgcn_cvt_pk_f32_fp8(d.y, false);
                acc0[3] += __builtin_amdgcn_cvt_pk_f32_fp8(d.y, true);
            }
#pragma unroll
            for (int t = 0; t < 8; ++t) {
                uint2v d = *reinterpret_cast<const uint2v*>(
                    qb + (size_t)((unsigned)nbrow[32 + rg * 8 + t] * 64u));
                acc1[0] += __builtin_amdgcn_cvt_pk_f32_fp8(d.x, false);
                acc1[1] += __builtin_amdgcn_cvt_pk_f32_fp8(d.x, true);
                acc1[2] += __builtin_amdgcn_cvt_pk_f32_fp8(d.y, false);
                acc1[3] += __builtin_amdgcn_cvt_pk_f32_fp8(d.y, true);
            }
#pragma unroll
            for (int t = 0; t < 8; ++t) {
                uint2v d = *reinterpret_cast<const uint2v*>(
                    qb + (size_t)((unsigned)nbrow[64 + rg * 8 + t] * 64u));
                acc2[0] += __builtin_amdgcn_cvt_pk_f32_fp8(d.x, false);
                acc2[1] += __builtin_amdgcn_cvt_pk_f32_fp8(d.x, true);
                acc2[2] += __builtin_amdgcn_cvt_pk_f32_fp8(d.y, false);
                acc2[3] += __builtin_amdgcn_cvt_pk_f32_fp8(d.y, true);
            }
            // combine the 4 row-groups (lane bits 3,4)
#pragma unroll
            for (int mm = 8; mm <= 16; mm <<= 1) {
#pragma unroll
                for (int q = 0; q < 4; ++q) {
                    acc0[q] += shfl_xor_f2(acc0[q], mm);
                    acc1[q] += shfl_xor_f2(acc1[q], mm);
                    acc2[q] += shfl_xor_f2(acc2[q], mm);
                }
            }
            if (rg < 2) {
                int n = n0 + m;
                const float* wt = swl + rg * 192 + 24 * e;
                float wv[24];
#pragma unroll
                for (int q = 0; q < 6; ++q) {
                    float4 tv = reinterpret_cast<const float4*>(wt)[q];
                    wv[4 * q] = tv.x; wv[4 * q + 1] = tv.y;
                    wv[4 * q + 2] = tv.z; wv[4 * q + 3] = tv.w;
                }
                const float inv = 1.f / 32.f;
                float o[8];
                half8 rh;
                if (rg == 0) {
#pragma unroll
                    for (int i = 0; i < 8; ++i) {
                        float a0 = acc0[i >> 1][i & 1] * inv;
                        float a1 = acc1[i >> 1][i & 1] * inv;
                        float a2 = acc2[i >> 1][i & 1] * inv;
                        o[i] = wv[3 * i] * a0 + wv[3 * i + 1] * a1 + wv[3 * i + 2] * a2;
                        rh[i] = (_Float16)o[i];
                    }
                } else {
                    half8 sv = *reinterpret_cast<const half8*>(h0h + (size_t)n * 64 + 8 * e);
#pragma unroll
                    for (int i = 0; i < 8; ++i) {
                        float a0 = acc0[i >> 1][i & 1] * inv;
                        float a1 = acc1[i >> 1][i & 1] * inv;
                        float a2 = acc2[i >> 1][i & 1] * inv;
                        float s = (float)sv[i];
                        o[i] = wv[3 * i] * (s - a0) + wv[3 * i + 1] * (s - a1) +
                               wv[3 * i + 2] * (s - a2);
                        rh[i] = (_Float16)o[i];
                    }
                }
                size_t base = (size_t)n * 128 + rg * 64 + 8 * e;
                __builtin_nontemporal_store(__builtin_bit_cast(int4v, rh),
                    reinterpret_cast<int4v*>(i1h + base));
                unsigned q0 = __builtin_amdgcn_cvt_pk_fp8_f32(o[0], o[1], 0u, false);
                q0 = __builtin_amdgcn_cvt_pk_fp8_f32(o[2], o[3], q0, true);
                unsigned q1 = __builtin_amdgcn_cvt_pk_fp8_f32(o[4], o[5], 0u, false);
                q1 = __builtin_amdgcn_cvt_pk_fp8_f32(o[6], o[7], q1, true);
                uint2v uq = {q0, q1};
                __builtin_nontemporal_store(uq, reinterpret_cast<uint2v*>(i1q + base));
            }
        }
    }
    grid_barrier(barrier_cnt + 32);

    // ============ Phase 3: layer-2 InterAgg (batch) + dense head ============
    if (bid < BATCH / 4) {
        int* nb3 = (int*)smraw;                 // 4*96 ints
        int* nid = (int*)(smraw + 1536);        // 4 ints
        float* swl3 = (float*)(smraw + 1552);   // 768 floats
        int b0 = bid * 4;
        if (tid < 4) nid[tid] = nodes[b0 + tid];
        if (tid >= 64 && tid < 256) {
            int q = tid - 64;
            reinterpret_cast<float4*>(swl3)[q] = reinterpret_cast<const float4*>(sw2)[q];
        }
        __syncthreads();
        for (int q = tid; q < 384; q += 256) {
            int local = q / 96, idx = q - local * 96;
            int r = idx >> 5, d = idx & 31;
            nb3[local * 96 + idx] = __builtin_nontemporal_load(
                adj + ((size_t)r * N_NODES + nid[local]) * DEG + d);
        }
        __syncthreads();
        int local = tid >> 6, j = tid & 63;
        int bb = b0 + local;
        int n = nid[local];
        int g = j >> 4, e = j & 15;
        int idxs[24];
#pragma unroll
        for (int t = 0; t < 24; ++t) idxs[t] = nb3[local * 96 + t * 4 + g];
        const unsigned char* qbase = i1q + 8 * e;
        f32x2 acc0[4] = {}, acc1[4] = {}, acc2[4] = {};
#pragma unroll
        for (int t = 0; t < 8; ++t) {
            uint2v d = *reinterpret_cast<const uint2v*>(
                qbase + (size_t)((unsigned)idxs[t] * 128u));
            acc0[0] += __builtin_amdgcn_cvt_pk_f32_fp8(d.x, false);
            acc0[1] += __builtin_amdgcn_cvt_pk_f32_fp8(d.x, true);
            acc0[2] += __builtin_amdgcn_cvt_pk_f32_fp8(d.y, false);
            acc0[3] += __builtin_amdgcn_cvt_pk_f32_fp8(d.y, true);
        }
#pragma unroll
        for (int t = 8; t < 16; ++t) {
            uint2v d = *reinterpret_cast<const uint2v*>(
                qbase + (size_t)((unsigned)idxs[t] * 128u));
            acc1[0] += __builtin_amdgcn_cvt_pk_f32_fp8(d.x, false);
            acc1[1] += __builtin_amdgcn_cvt_pk_f32_fp8(d.x, true);
            acc1[2] += __builtin_amdgcn_cvt_pk_f32_fp8(d.y, false);
            acc1[3] += __builtin_amdgcn_cvt_pk_f32_fp8(d.y, true);
        }
#pragma unroll
        for (int t = 16; t < 24; ++t) {
            uint2v d = *reinterpret_cast<const uint2v*>(
                qbase + (size_t)((unsigned)idxs[t] * 128u));
            acc2[0] += __builtin_amdgcn_cvt_pk_f32_fp8(d.x, false);
            acc2[1] += __builtin_amdgcn_cvt_pk_f32_fp8(d.x, true);
            acc2[2] += __builtin_amdgcn_cvt_pk_f32_fp8(d.y, false);
            acc2[3] += __builtin_amdgcn_cvt_pk_f32_fp8(d.y, true);
        }
#pragma unroll
        for (int mm = 16; mm <= 32; mm <<= 1) {
#pragma unroll
            for (int q = 0; q < 4; ++q) {
                acc0[q] += shfl_xor_f2(acc0[q], mm);
                acc1[q] += shfl_xor_f2(acc1[q], mm);
                acc2[q] += shfl_xor_f2(acc2[q], mm);
            }
        }
        const float inv = 1.f / 32.f;
        float p0 = 0.f, p1 = 0.f;
        if (g == 0) {
            half8 sv = *reinterpret_cast<const half8*>(i1h + (size_t)n * 128 + 8 * e);
            const float* wa = swl3 + 24 * e;
            const float* wb = swl3 + 384 + 24 * e;
#pragma unroll
            for (int i = 0; i < 8; ++i) {
                int f = 8 * e + i;
                float a0 = acc0[i >> 1][i & 1] * inv;
                float a1 = acc1[i >> 1][i & 1] * inv;
                float a2 = acc2[i >> 1][i & 1] * inv;
                float s = (float)sv[i];
                float i2a = wa[3 * i] * a0 + wa[3 * i + 1] * a1 + wa[3 * i + 2] * a2;
                float i2b = wb[3 * i] * (s - a0) + wb[3 * i + 1] * (s - a1) +
                            wb[3 * i + 2] * (s - a2);
                p0 += i2a * w_d2[(192 + f) * 2 + 0] + i2b * w_d2[(320 + f) * 2 + 0];
                p1 += i2a * w_d2[(192 + f) * 2 + 1] + i2b * w_d2[(320 + f) * 2 + 1];
            }
        } else if (g == 1) {
#pragma unroll
            for (int i = 0; i < 4; ++i) {
                int f = 4 * e + i;
                float s = (float)h0h[(size_t)n * 64 + f];
                p0 += s * w_d2[f * 2 + 0];
                p1 += s * w_d2[f * 2 + 1];
            }
        } else if (g == 2) {
            half8 sv = *reinterpret_cast<const half8*>(i1h + (size_t)n * 128 + 8 * e);
#pragma unroll
            for (int i = 0; i < 8; ++i) {
                int f = 8 * e + i;
                float s = (float)sv[i];
                p0 += s * w_d2[(64 + f) * 2 + 0];
                p1 += s * w_d2[(64 + f) * 2 + 1];
            }
        }
#pragma unroll
        for (int mm = 1; mm <= 32; mm <<= 1) {
            p0 += __shfl_xor(p0, mm, 64);
            p1 += __shfl_xor(p1, mm, 64);
        }
        if (j == 0) {
            float x0 = p0 + b_d2[0], x1 = p1 + b_d2[1];
            x0 = x0 > 0.f ? x0 : 0.3f * x0;
            x1 = x1 > 0.f ? x1 : 0.3f * x1;
            x0 += __logf(prior[0]);
            x1 += __logf(prior[1]);
            float z = x0 * w_d1[0] + x1 * w_d1[1] + b_d1[0];
            out[bb] = 1.f / (1.f + __expf(-z));
        }
    }
}

extern "C" void kernel_launch(void* const* d_in, const int* in_sizes, int n_in,
                              void* d_out, int out_size, void* d_ws, size_t ws_size,
                              hipStream_t stream) {
    const int*   nodes  = (const int*)d_in[0];
    const float* feat   = (const float*)d_in[1];
    const int*   adj    = (const int*)d_in[2];
    const float* prior  = (const float*)d_in[3];
    const float* w_mlp  = (const float*)d_in[4];
    const float* b_mlp  = (const float*)d_in[5];
    const float* alpha1 = (const float*)d_in[6];
    const float* alpha2 = (const float*)d_in[7];
    const float* w_d2   = (const float*)d_in[8];
    const float* b_d2   = (const float*)d_in[9];
    const float* w_d1   = (const float*)d_in[10];
    const float* b_d1   = (const float*)d_in[11];
    float* out = (float*)d_out;

    // ws: sw1(384f) | sw2(768f) | pad->8192 | h0h fp16 N*64 | i1h fp16 N*128 |
    //     h0q fp8 N*64 | i1q fp8 N*128 | ... | barrier counters @ +32MB
    float* sw1 = (float*)d_ws;
    float* sw2 = sw1 + 128 * 3;
    _Float16* h0h = (_Float16*)((char*)d_ws + 8192);
    _Float16* i1h = h0h + (size_t)N_NODES * 64;
    unsigned char* h0q = (unsigned char*)(i1h + (size_t)N_NODES * 128);
    unsigned char* i1q = h0q + (size_t)N_NODES * 64;
    int* barrier_cnt = (int*)((char*)d_ws + (size_t)32 * 1024 * 1024);

    hipMemsetAsync(barrier_cnt, 0, 256, stream);
    fused_kernel<<<GRID_BLKS, 256, 0, stream>>>(
        nodes, feat, adj, prior, w_mlp, b_mlp, alpha1, alpha2,
        w_d2, b_d2, w_d1, b_d1, sw1, sw2, h0h, h0q, i1h, i1q,
        barrier_cnt, out);
}

// Round 10
// 59.055 us; speedup vs baseline: 7.3432x; 6.2734x over previous
//
#include <hip/hip_runtime.h>
#include <hip/hip_fp16.h>
#include <math.h>

#define N_NODES 50000
#define F_IN 32
#define DEG 32
#define BATCH 2048
#define NB_STRIDE 100  // ints per staged index row: 96 + 4 pad

typedef _Float16 half8 __attribute__((ext_vector_type(8)));
typedef _Float16 half2v __attribute__((ext_vector_type(2)));
typedef int int4v __attribute__((ext_vector_type(4)));
typedef unsigned int uint2v __attribute__((ext_vector_type(2)));
typedef float f32x2 __attribute__((ext_vector_type(2)));

__device__ __forceinline__ void softmax3(float a0, float a1, float a2,
                                         float& w0, float& w1, float& w2) {
    float m = fmaxf(a0, fmaxf(a1, a2));
    float e0 = __expf(a0 - m), e1 = __expf(a1 - m), e2 = __expf(a2 - m);
    float s = 1.f / (e0 + e1 + e2);
    w0 = e0 * s; w1 = e1 * s; w2 = e2 * s;
}

__device__ __forceinline__ f32x2 shfl_xor_f2(f32x2 v, int m) {
    v.x = __shfl_xor(v.x, m, 64);
    v.y = __shfl_xor(v.y, m, 64);
    return v;
}

// ---- Kernel A: h0 = relu(feat @ w_mlp + b) -> fp16 master + fp8 gather copy.
// 8 nodes / 256-thread block, 2 features per thread. Grid-strided.
__global__ __launch_bounds__(256) void mlp_kernel(
        const float* __restrict__ feat,
        const float* __restrict__ w,
        const float* __restrict__ b,
        const float* __restrict__ alpha1,
        const float* __restrict__ alpha2,
        float* __restrict__ sw1,    // 128*3
        float* __restrict__ sw2,    // 256*3
        _Float16* __restrict__ h0h,
        unsigned char* __restrict__ h0q) {
    __shared__ float wl[F_IN * 64];
    __shared__ float fl[8 * F_IN];
    int tid = threadIdx.x;
    if (blockIdx.x == 0) {
        for (int q = tid; q < 384; q += 256) {
            const float* src = (q < 128) ? (alpha1 + q * 3) : (alpha2 + (q - 128) * 3);
            float* dst = (q < 128) ? (sw1 + q * 3) : (sw2 + (q - 128) * 3);
            float w0, w1, w2;
            softmax3(src[0], src[1], src[2], w0, w1, w2);
            dst[0] = w0; dst[1] = w1; dst[2] = w2;
        }
    }
    for (int i = tid; i < F_IN * 64; i += 256) wl[i] = w[i];
    int local = tid >> 5;        // node 0..7
    int f2 = (tid & 31) * 2;     // feature pair
    float b0 = b[f2], b1 = b[f2 + 1];
    const int noct = N_NODES / 8;  // 6250
    for (int q = blockIdx.x; q < noct; q += gridDim.x) {
        int n0 = q * 8;
        __syncthreads();  // protect fl from previous iteration's readers
        fl[tid] = __builtin_nontemporal_load(feat + (size_t)n0 * F_IN + tid);
        __syncthreads();
        float a0 = b0, a1 = b1;
#pragma unroll
        for (int k = 0; k < F_IN; ++k) {
            float v = fl[local * F_IN + k];
            a0 = fmaf(v, wl[k * 64 + f2], a0);
            a1 = fmaf(v, wl[k * 64 + f2 + 1], a1);
        }
        a0 = fmaxf(a0, 0.f);
        a1 = fmaxf(a1, 0.f);
        int n = n0 + local;
        half2v hv = {(_Float16)a0, (_Float16)a1};
        *reinterpret_cast<half2v*>(h0h + (size_t)n * 64 + f2) = hv;
        unsigned pk = __builtin_amdgcn_cvt_pk_fp8_f32(a0, a1, 0u, false);
        *reinterpret_cast<unsigned short*>(h0q + (size_t)n * 64 + f2) =
            (unsigned short)pk;
    }
}

// ---- Kernel B: layer-1 InterAgg. 16 nodes / 128-thread block (8 nodes per
// wave, lane = (node, octet)), 3125 blocks -> ~24 waves/CU for latency hiding.
// Gathers from fp8 h0q (L2-resident 3.2 MB); self from fp16 h0h.
__global__ __launch_bounds__(128) void layer1_kernel(
        const int* __restrict__ adj,
        const unsigned char* __restrict__ h0q,
        const _Float16* __restrict__ h0h,
        const float* __restrict__ sw1,
        _Float16* __restrict__ i1h,
        unsigned char* __restrict__ i1q) {
    __shared__ int nb[16 * NB_STRIDE];  // 6.4 KB
    __shared__ float swl[384];          // wA(192) | wB(192)
    int tid = threadIdx.x;
    int n0 = blockIdx.x * 16;
    if (tid < 96)
        reinterpret_cast<float4*>(swl)[tid] = reinterpret_cast<const float4*>(sw1)[tid];
    // stage adj: 3 relations x 16 nodes x 32 deg = 384 int4, 3 per lane
#pragma unroll
    for (int q = tid; q < 384; q += 128) {
        int r = q >> 7;            // 0..2
        int idx = q & 127;
        int m = idx >> 3;          // node local 0..15
        int d4 = (idx & 7) * 4;
        int4v v = __builtin_nontemporal_load(reinterpret_cast<const int4v*>(
                adj + ((size_t)r * N_NODES + (n0 + m)) * DEG + d4));
        *reinterpret_cast<int4v*>(&nb[m * NB_STRIDE + r * 32 + d4]) = v;
    }
    __syncthreads();
    int w = tid >> 6, j = tid & 63;
    int m = w * 8 + (j >> 3);      // node local 0..15
    int e = j & 7;                 // feature octet
    int n = n0 + m;
    const int* nbrow = nb + m * NB_STRIDE;
    const unsigned char* qb = h0q + 8 * e;
    f32x2 acc0[4] = {}, acc1[4] = {}, acc2[4] = {};
#pragma unroll 8
    for (int t = 0; t < 32; ++t) {
        uint2v d = *reinterpret_cast<const uint2v*>(qb + (size_t)((unsigned)nbrow[t] * 64u));
        acc0[0] += __builtin_amdgcn_cvt_pk_f32_fp8(d.x, false);
        acc0[1] += __builtin_amdgcn_cvt_pk_f32_fp8(d.x, true);
        acc0[2] += __builtin_amdgcn_cvt_pk_f32_fp8(d.y, false);
        acc0[3] += __builtin_amdgcn_cvt_pk_f32_fp8(d.y, true);
    }
#pragma unroll 8
    for (int t = 32; t < 64; ++t) {
        uint2v d = *reinterpret_cast<const uint2v*>(qb + (size_t)((unsigned)nbrow[t] * 64u));
        acc1[0] += __builtin_amdgcn_cvt_pk_f32_fp8(d.x, false);
        acc1[1] += __builtin_amdgcn_cvt_pk_f32_fp8(d.x, true);
        acc1[2] += __builtin_amdgcn_cvt_pk_f32_fp8(d.y, false);
        acc1[3] += __builtin_amdgcn_cvt_pk_f32_fp8(d.y, true);
    }
#pragma unroll 8
    for (int t = 64; t < 96; ++t) {
        uint2v d = *reinterpret_cast<const uint2v*>(qb + (size_t)((unsigned)nbrow[t] * 64u));
        acc2[0] += __builtin_amdgcn_cvt_pk_f32_fp8(d.x, false);
        acc2[1] += __builtin_amdgcn_cvt_pk_f32_fp8(d.x, true);
        acc2[2] += __builtin_amdgcn_cvt_pk_f32_fp8(d.y, false);
        acc2[3] += __builtin_amdgcn_cvt_pk_f32_fp8(d.y, true);
    }

    half8 sv = *reinterpret_cast<const half8*>(h0h + (size_t)n * 64 + 8 * e);
    float wA[24], wB[24];
    {
        const float4* pa = reinterpret_cast<const float4*>(swl + 24 * e);
        const float4* pb = reinterpret_cast<const float4*>(swl + 192 + 24 * e);
#pragma unroll
        for (int q = 0; q < 6; ++q) {
            float4 ta = pa[q], tb = pb[q];
            wA[4 * q] = ta.x; wA[4 * q + 1] = ta.y; wA[4 * q + 2] = ta.z; wA[4 * q + 3] = ta.w;
            wB[4 * q] = tb.x; wB[4 * q + 1] = tb.y; wB[4 * q + 2] = tb.z; wB[4 * q + 3] = tb.w;
        }
    }
    const float inv = 1.f / 32.f;
    float oa[8], ob[8];
    half8 ra, rb;
#pragma unroll
    for (int i = 0; i < 8; ++i) {
        float a0 = acc0[i >> 1][i & 1] * inv;
        float a1 = acc1[i >> 1][i & 1] * inv;
        float a2 = acc2[i >> 1][i & 1] * inv;
        float s = (float)sv[i];
        oa[i] = wA[3 * i] * a0 + wA[3 * i + 1] * a1 + wA[3 * i + 2] * a2;
        ob[i] = wB[3 * i] * (s - a0) + wB[3 * i + 1] * (s - a1) + wB[3 * i + 2] * (s - a2);
        ra[i] = (_Float16)oa[i];
        rb[i] = (_Float16)ob[i];
    }
    __builtin_nontemporal_store(__builtin_bit_cast(int4v, ra),
        reinterpret_cast<int4v*>(i1h + (size_t)n * 128 + 8 * e));
    __builtin_nontemporal_store(__builtin_bit_cast(int4v, rb),
        reinterpret_cast<int4v*>(i1h + (size_t)n * 128 + 64 + 8 * e));
    unsigned qa0 = __builtin_amdgcn_cvt_pk_fp8_f32(oa[0], oa[1], 0u, false);
    qa0 = __builtin_amdgcn_cvt_pk_fp8_f32(oa[2], oa[3], qa0, true);
    unsigned qa1 = __builtin_amdgcn_cvt_pk_fp8_f32(oa[4], oa[5], 0u, false);
    qa1 = __builtin_amdgcn_cvt_pk_fp8_f32(oa[6], oa[7], qa1, true);
    uint2v ua = {qa0, qa1};
    __builtin_nontemporal_store(ua,
        reinterpret_cast<uint2v*>(i1q + (size_t)n * 128 + 8 * e));
    unsigned qb0 = __builtin_amdgcn_cvt_pk_fp8_f32(ob[0], ob[1], 0u, false);
    qb0 = __builtin_amdgcn_cvt_pk_fp8_f32(ob[2], ob[3], qb0, true);
    unsigned qb1 = __builtin_amdgcn_cvt_pk_fp8_f32(ob[4], ob[5], 0u, false);
    qb1 = __builtin_amdgcn_cvt_pk_fp8_f32(ob[6], ob[7], qb1, true);
    uint2v ub = {qb0, qb1};
    __builtin_nontemporal_store(ub,
        reinterpret_cast<uint2v*>(i1q + (size_t)n * 128 + 64 + 8 * e));
}

// ---- Kernel C: layer-2 InterAgg + fused dense head. 1 node per 64-thread
// block (2048 blocks -> 8 waves/CU floor, no cross-wave sync needed).
__global__ __launch_bounds__(64) void layer2_kernel(
        const int* __restrict__ nodes,
        const int* __restrict__ adj,
        const _Float16* __restrict__ h0h,
        const _Float16* __restrict__ i1h,
        const unsigned char* __restrict__ i1q,
        const float* __restrict__ sw2,
        const float* __restrict__ w_d2,
        const float* __restrict__ b_d2,
        const float* __restrict__ w_d1,
        const float* __restrict__ b_d1,
        const float* __restrict__ prior,
        float* __restrict__ out) {
    __shared__ int nb[96];
    __shared__ float swl[768];  // wA(384) | wB(384)
    int tid = threadIdx.x;
    int bb = blockIdx.x;
    int n = nodes[bb];
#pragma unroll
    for (int q = tid; q < 192; q += 64)
        reinterpret_cast<float4*>(swl)[q] = reinterpret_cast<const float4*>(sw2)[q];
    if (tid < 24) {
        int r = tid >> 3, d4 = (tid & 7) * 4;
        int4v v = __builtin_nontemporal_load(reinterpret_cast<const int4v*>(
                adj + ((size_t)r * N_NODES + n) * DEG + d4));
        *reinterpret_cast<int4v*>(&nb[r * 32 + d4]) = v;
    }
    __syncthreads();
    int j = tid;
    int g = j >> 4, e = j & 15;
    int idxs[24];
#pragma unroll
    for (int t = 0; t < 24; ++t) idxs[t] = nb[t * 4 + g];
    const unsigned char* qbase = i1q + 8 * e;
    f32x2 acc0[4] = {}, acc1[4] = {}, acc2[4] = {};
#pragma unroll
    for (int t = 0; t < 8; ++t) {
        uint2v d = *reinterpret_cast<const uint2v*>(
            qbase + (size_t)((unsigned)idxs[t] * 128u));
        acc0[0] += __builtin_amdgcn_cvt_pk_f32_fp8(d.x, false);
        acc0[1] += __builtin_amdgcn_cvt_pk_f32_fp8(d.x, true);
        acc0[2] += __builtin_amdgcn_cvt_pk_f32_fp8(d.y, false);
        acc0[3] += __builtin_amdgcn_cvt_pk_f32_fp8(d.y, true);
    }
#pragma unroll
    for (int t = 8; t < 16; ++t) {
        uint2v d = *reinterpret_cast<const uint2v*>(
            qbase + (size_t)((unsigned)idxs[t] * 128u));
        acc1[0] += __builtin_amdgcn_cvt_pk_f32_fp8(d.x, false);
        acc1[1] += __builtin_amdgcn_cvt_pk_f32_fp8(d.x, true);
        acc1[2] += __builtin_amdgcn_cvt_pk_f32_fp8(d.y, false);
        acc1[3] += __builtin_amdgcn_cvt_pk_f32_fp8(d.y, true);
    }
#pragma unroll
    for (int t = 16; t < 24; ++t) {
        uint2v d = *reinterpret_cast<const uint2v*>(
            qbase + (size_t)((unsigned)idxs[t] * 128u));
        acc2[0] += __builtin_amdgcn_cvt_pk_f32_fp8(d.x, false);
        acc2[1] += __builtin_amdgcn_cvt_pk_f32_fp8(d.x, true);
        acc2[2] += __builtin_amdgcn_cvt_pk_f32_fp8(d.y, false);
        acc2[3] += __builtin_amdgcn_cvt_pk_f32_fp8(d.y, true);
    }
#pragma unroll
    for (int mm = 16; mm <= 32; mm <<= 1) {
#pragma unroll
        for (int q = 0; q < 4; ++q) {
            acc0[q] += shfl_xor_f2(acc0[q], mm);
            acc1[q] += shfl_xor_f2(acc1[q], mm);
            acc2[q] += shfl_xor_f2(acc2[q], mm);
        }
    }
    const float inv = 1.f / 32.f;
    float p0 = 0.f, p1 = 0.f;
    if (g == 0) {
        half8 sv = *reinterpret_cast<const half8*>(i1h + (size_t)n * 128 + 8 * e);
        const float* wa = swl + 24 * e;
        const float* wb = swl + 384 + 24 * e;
#pragma unroll
        for (int i = 0; i < 8; ++i) {
            int f = 8 * e + i;
            float a0 = acc0[i >> 1][i & 1] * inv;
            float a1 = acc1[i >> 1][i & 1] * inv;
            float a2 = acc2[i >> 1][i & 1] * inv;
            float s = (float)sv[i];
            float i2a = wa[3 * i] * a0 + wa[3 * i + 1] * a1 + wa[3 * i + 2] * a2;
            float i2b = wb[3 * i] * (s - a0) + wb[3 * i + 1] * (s - a1) +
                        wb[3 * i + 2] * (s - a2);
            p0 += i2a * w_d2[(192 + f) * 2 + 0] + i2b * w_d2[(320 + f) * 2 + 0];
            p1 += i2a * w_d2[(192 + f) * 2 + 1] + i2b * w_d2[(320 + f) * 2 + 1];
        }
    } else if (g == 1) {
#pragma unroll
        for (int i = 0; i < 4; ++i) {
            int f = 4 * e + i;
            float s = (float)h0h[(size_t)n * 64 + f];
            p0 += s * w_d2[f * 2 + 0];
            p1 += s * w_d2[f * 2 + 1];
        }
    } else if (g == 2) {
        half8 sv = *reinterpret_cast<const half8*>(i1h + (size_t)n * 128 + 8 * e);
#pragma unroll
        for (int i = 0; i < 8; ++i) {
            int f = 8 * e + i;
            float s = (float)sv[i];
            p0 += s * w_d2[(64 + f) * 2 + 0];
            p1 += s * w_d2[(64 + f) * 2 + 1];
        }
    }
#pragma unroll
    for (int mm = 1; mm <= 32; mm <<= 1) {
        p0 += __shfl_xor(p0, mm, 64);
        p1 += __shfl_xor(p1, mm, 64);
    }
    if (j == 0) {
        float x0 = p0 + b_d2[0], x1 = p1 + b_d2[1];
        x0 = x0 > 0.f ? x0 : 0.3f * x0;
        x1 = x1 > 0.f ? x1 : 0.3f * x1;
        x0 += __logf(prior[0]);
        x1 += __logf(prior[1]);
        float z = x0 * w_d1[0] + x1 * w_d1[1] + b_d1[0];
        out[bb] = 1.f / (1.f + __expf(-z));
    }
}

extern "C" void kernel_launch(void* const* d_in, const int* in_sizes, int n_in,
                              void* d_out, int out_size, void* d_ws, size_t ws_size,
                              hipStream_t stream) {
    const int*   nodes  = (const int*)d_in[0];
    const float* feat   = (const float*)d_in[1];
    const int*   adj    = (const int*)d_in[2];
    const float* prior  = (const float*)d_in[3];
    const float* w_mlp  = (const float*)d_in[4];
    const float* b_mlp  = (const float*)d_in[5];
    const float* alpha1 = (const float*)d_in[6];
    const float* alpha2 = (const float*)d_in[7];
    const float* w_d2   = (const float*)d_in[8];
    const float* b_d2   = (const float*)d_in[9];
    const float* w_d1   = (const float*)d_in[10];
    const float* b_d1   = (const float*)d_in[11];
    float* out = (float*)d_out;

    // ws: sw1(384f) | sw2(768f) | pad->8192 | h0h fp16 N*64 | i1h fp16 N*128 |
    //     h0q fp8 N*64 | i1q fp8 N*128
    float* sw1 = (float*)d_ws;
    float* sw2 = sw1 + 128 * 3;
    _Float16* h0h = (_Float16*)((char*)d_ws + 8192);
    _Float16* i1h = h0h + (size_t)N_NODES * 64;
    unsigned char* h0q = (unsigned char*)(i1h + (size_t)N_NODES * 128);
    unsigned char* i1q = h0q + (size_t)N_NODES * 64;

    mlp_kernel<<<2048, 256, 0, stream>>>(feat, w_mlp, b_mlp, alpha1, alpha2,
                                         sw1, sw2, h0h, h0q);
    layer1_kernel<<<N_NODES / 16, 128, 0, stream>>>(adj, h0q, h0h, sw1, i1h, i1q);
    layer2_kernel<<<BATCH, 64, 0, stream>>>(nodes, adj, h0h, i1h, i1q, sw2,
                                            w_d2, b_d2, w_d1, b_d1, prior, out);
}

// Round 11
// 55.424 us; speedup vs baseline: 7.8243x; 1.0655x over previous
//
#include <hip/hip_runtime.h>
#include <hip/hip_fp16.h>
#include <math.h>

#define N_NODES 50000
#define F_IN 32
#define DEG 32
#define BATCH 2048
#define NB_STRIDE 100  // ints per staged index row: 96 + 4 pad

typedef int int4v __attribute__((ext_vector_type(4)));
typedef unsigned int uint2v __attribute__((ext_vector_type(2)));
typedef float f32x2 __attribute__((ext_vector_type(2)));

__device__ __forceinline__ void softmax3(float a0, float a1, float a2,
                                         float& w0, float& w1, float& w2) {
    float m = fmaxf(a0, fmaxf(a1, a2));
    float e0 = __expf(a0 - m), e1 = __expf(a1 - m), e2 = __expf(a2 - m);
    float s = 1.f / (e0 + e1 + e2);
    w0 = e0 * s; w1 = e1 * s; w2 = e2 * s;
}

__device__ __forceinline__ f32x2 shfl_xor_f2(f32x2 v, int m) {
    v.x = __shfl_xor(v.x, m, 64);
    v.y = __shfl_xor(v.y, m, 64);
    return v;
}

// ---- Kernel A: h0 = relu(feat @ w_mlp + b) -> fp8 table only.
// 8 nodes / 256-thread block, 2 features per thread. Grid-strided.
__global__ __launch_bounds__(256) void mlp_kernel(
        const float* __restrict__ feat,
        const float* __restrict__ w,
        const float* __restrict__ b,
        const float* __restrict__ alpha1,
        const float* __restrict__ alpha2,
        float* __restrict__ sw1,    // 128*3
        float* __restrict__ sw2,    // 256*3
        unsigned char* __restrict__ h0q) {
    __shared__ float wl[F_IN * 64];
    __shared__ float fl[8 * F_IN];
    int tid = threadIdx.x;
    if (blockIdx.x == 0) {
        for (int q = tid; q < 384; q += 256) {
            const float* src = (q < 128) ? (alpha1 + q * 3) : (alpha2 + (q - 128) * 3);
            float* dst = (q < 128) ? (sw1 + q * 3) : (sw2 + (q - 128) * 3);
            float w0, w1, w2;
            softmax3(src[0], src[1], src[2], w0, w1, w2);
            dst[0] = w0; dst[1] = w1; dst[2] = w2;
        }
    }
    for (int i = tid; i < F_IN * 64; i += 256) wl[i] = w[i];
    int local = tid >> 5;        // node 0..7
    int f2 = (tid & 31) * 2;     // feature pair
    float b0 = b[f2], b1 = b[f2 + 1];
    const int noct = N_NODES / 8;  // 6250
    for (int q = blockIdx.x; q < noct; q += gridDim.x) {
        int n0 = q * 8;
        __syncthreads();  // protect fl from previous iteration's readers
        fl[tid] = __builtin_nontemporal_load(feat + (size_t)n0 * F_IN + tid);
        __syncthreads();
        float a0 = b0, a1 = b1;
#pragma unroll
        for (int k = 0; k < F_IN; ++k) {
            float v = fl[local * F_IN + k];
            a0 = fmaf(v, wl[k * 64 + f2], a0);
            a1 = fmaf(v, wl[k * 64 + f2 + 1], a1);
        }
        a0 = fmaxf(a0, 0.f);
        a1 = fmaxf(a1, 0.f);
        int n = n0 + local;
        unsigned pk = __builtin_amdgcn_cvt_pk_fp8_f32(a0, a1, 0u, false);
        *reinterpret_cast<unsigned short*>(h0q + (size_t)n * 64 + f2) =
            (unsigned short)pk;
    }
}

// ---- Kernel B: layer-1 InterAgg. 16 nodes / 128-thread block, 8 nodes/wave,
// lane = (node, octet). All reads from fp8 h0q (L2-resident 3.2 MB).
__global__ __launch_bounds__(128) void layer1_kernel(
        const int* __restrict__ adj,
        const unsigned char* __restrict__ h0q,
        const float* __restrict__ sw1,
        unsigned char* __restrict__ i1q) {
    __shared__ int nb[16 * NB_STRIDE];  // 6.4 KB
    __shared__ float swl[384];          // wA(192) | wB(192)
    int tid = threadIdx.x;
    int n0 = blockIdx.x * 16;
    if (tid < 96)
        reinterpret_cast<float4*>(swl)[tid] = reinterpret_cast<const float4*>(sw1)[tid];
    // stage adj: 3 relations x 16 nodes x 32 deg = 384 int4, 3 per lane
#pragma unroll
    for (int q = tid; q < 384; q += 128) {
        int r = q >> 7;            // 0..2
        int idx = q & 127;
        int m = idx >> 3;          // node local 0..15
        int d4 = (idx & 7) * 4;
        int4v v = __builtin_nontemporal_load(reinterpret_cast<const int4v*>(
                adj + ((size_t)r * N_NODES + (n0 + m)) * DEG + d4));
        *reinterpret_cast<int4v*>(&nb[m * NB_STRIDE + r * 32 + d4]) = v;
    }
    __syncthreads();
    int w = tid >> 6, j = tid & 63;
    int m = w * 8 + (j >> 3);      // node local 0..15
    int e = j & 7;                 // feature octet
    int n = n0 + m;
    const int* nbrow = nb + m * NB_STRIDE;
    const unsigned char* qb = h0q + 8 * e;
    f32x2 acc0[4] = {}, acc1[4] = {}, acc2[4] = {};
#pragma unroll 8
    for (int t = 0; t < 32; ++t) {
        uint2v d = *reinterpret_cast<const uint2v*>(qb + (size_t)((unsigned)nbrow[t] * 64u));
        acc0[0] += __builtin_amdgcn_cvt_pk_f32_fp8(d.x, false);
        acc0[1] += __builtin_amdgcn_cvt_pk_f32_fp8(d.x, true);
        acc0[2] += __builtin_amdgcn_cvt_pk_f32_fp8(d.y, false);
        acc0[3] += __builtin_amdgcn_cvt_pk_f32_fp8(d.y, true);
    }
#pragma unroll 8
    for (int t = 32; t < 64; ++t) {
        uint2v d = *reinterpret_cast<const uint2v*>(qb + (size_t)((unsigned)nbrow[t] * 64u));
        acc1[0] += __builtin_amdgcn_cvt_pk_f32_fp8(d.x, false);
        acc1[1] += __builtin_amdgcn_cvt_pk_f32_fp8(d.x, true);
        acc1[2] += __builtin_amdgcn_cvt_pk_f32_fp8(d.y, false);
        acc1[3] += __builtin_amdgcn_cvt_pk_f32_fp8(d.y, true);
    }
#pragma unroll 8
    for (int t = 64; t < 96; ++t) {
        uint2v d = *reinterpret_cast<const uint2v*>(qb + (size_t)((unsigned)nbrow[t] * 64u));
        acc2[0] += __builtin_amdgcn_cvt_pk_f32_fp8(d.x, false);
        acc2[1] += __builtin_amdgcn_cvt_pk_f32_fp8(d.x, true);
        acc2[2] += __builtin_amdgcn_cvt_pk_f32_fp8(d.y, false);
        acc2[3] += __builtin_amdgcn_cvt_pk_f32_fp8(d.y, true);
    }

    // self row from fp8 (same byte layout as gathers)
    float sarr[8];
    {
        uint2v sd = *reinterpret_cast<const uint2v*>(qb + (size_t)((unsigned)n * 64u));
        f32x2 s0 = __builtin_amdgcn_cvt_pk_f32_fp8(sd.x, false);
        f32x2 s1 = __builtin_amdgcn_cvt_pk_f32_fp8(sd.x, true);
        f32x2 s2 = __builtin_amdgcn_cvt_pk_f32_fp8(sd.y, false);
        f32x2 s3 = __builtin_amdgcn_cvt_pk_f32_fp8(sd.y, true);
        sarr[0] = s0.x; sarr[1] = s0.y; sarr[2] = s1.x; sarr[3] = s1.y;
        sarr[4] = s2.x; sarr[5] = s2.y; sarr[6] = s3.x; sarr[7] = s3.y;
    }
    float wA[24], wB[24];
    {
        const float4* pa = reinterpret_cast<const float4*>(swl + 24 * e);
        const float4* pb = reinterpret_cast<const float4*>(swl + 192 + 24 * e);
#pragma unroll
        for (int q = 0; q < 6; ++q) {
            float4 ta = pa[q], tb = pb[q];
            wA[4 * q] = ta.x; wA[4 * q + 1] = ta.y; wA[4 * q + 2] = ta.z; wA[4 * q + 3] = ta.w;
            wB[4 * q] = tb.x; wB[4 * q + 1] = tb.y; wB[4 * q + 2] = tb.z; wB[4 * q + 3] = tb.w;
        }
    }
    const float inv = 1.f / 32.f;
    float oa[8], ob[8];
#pragma unroll
    for (int i = 0; i < 8; ++i) {
        float a0 = acc0[i >> 1][i & 1] * inv;
        float a1 = acc1[i >> 1][i & 1] * inv;
        float a2 = acc2[i >> 1][i & 1] * inv;
        float s = sarr[i];
        oa[i] = wA[3 * i] * a0 + wA[3 * i + 1] * a1 + wA[3 * i + 2] * a2;
        ob[i] = wB[3 * i] * (s - a0) + wB[3 * i + 1] * (s - a1) + wB[3 * i + 2] * (s - a2);
    }
    unsigned qa0 = __builtin_amdgcn_cvt_pk_fp8_f32(oa[0], oa[1], 0u, false);
    qa0 = __builtin_amdgcn_cvt_pk_fp8_f32(oa[2], oa[3], qa0, true);
    unsigned qa1 = __builtin_amdgcn_cvt_pk_fp8_f32(oa[4], oa[5], 0u, false);
    qa1 = __builtin_amdgcn_cvt_pk_fp8_f32(oa[6], oa[7], qa1, true);
    uint2v ua = {qa0, qa1};
    __builtin_nontemporal_store(ua,
        reinterpret_cast<uint2v*>(i1q + (size_t)n * 128 + 8 * e));
    unsigned qb0 = __builtin_amdgcn_cvt_pk_fp8_f32(ob[0], ob[1], 0u, false);
    qb0 = __builtin_amdgcn_cvt_pk_fp8_f32(ob[2], ob[3], qb0, true);
    unsigned qb1 = __builtin_amdgcn_cvt_pk_fp8_f32(ob[4], ob[5], 0u, false);
    qb1 = __builtin_amdgcn_cvt_pk_fp8_f32(ob[6], ob[7], qb1, true);
    uint2v ub = {qb0, qb1};
    __builtin_nontemporal_store(ub,
        reinterpret_cast<uint2v*>(i1q + (size_t)n * 128 + 64 + 8 * e));
}

// ---- Kernel C: layer-2 InterAgg + fused dense head.
// 4 batch nodes / 256-thread block, one wave per node. All fp8 reads.
__global__ __launch_bounds__(256) void layer2_kernel(
        const int* __restrict__ nodes,
        const int* __restrict__ adj,
        const unsigned char* __restrict__ h0q,
        const unsigned char* __restrict__ i1q,
        const float* __restrict__ sw2,
        const float* __restrict__ w_d2,
        const float* __restrict__ b_d2,
        const float* __restrict__ w_d1,
        const float* __restrict__ b_d1,
        const float* __restrict__ prior,
        float* __restrict__ out) {
    __shared__ int nb[4][96];
    __shared__ int nid[4];
    __shared__ float swl[768];  // wA(384) | wB(384)
    int tid = threadIdx.x;
    int b0 = blockIdx.x * 4;
    if (tid < 4) nid[tid] = nodes[b0 + tid];
    if (tid >= 64 && tid < 256) {
        int q = tid - 64;
        reinterpret_cast<float4*>(swl)[q] = reinterpret_cast<const float4*>(sw2)[q];
    }
    __syncthreads();
    if (tid < 96) {
        int local = tid / 24, rem = tid - local * 24;
        int r = rem >> 3, d4 = (rem & 7) * 4;
        int4v v = __builtin_nontemporal_load(reinterpret_cast<const int4v*>(
                adj + ((size_t)r * N_NODES + nid[local]) * DEG + d4));
        *reinterpret_cast<int4v*>(&nb[local][r * 32 + d4]) = v;
    }
    __syncthreads();
    int local = tid >> 6, j = tid & 63;
    int bb = b0 + local;
    int n = nid[local];
    int g = j >> 4, e = j & 15;
    int idxs[24];
#pragma unroll
    for (int t = 0; t < 24; ++t) idxs[t] = nb[local][t * 4 + g];
    const unsigned char* qbase = i1q + 8 * e;
    f32x2 acc0[4] = {}, acc1[4] = {}, acc2[4] = {};
#pragma unroll
    for (int t = 0; t < 8; ++t) {
        uint2v d = *reinterpret_cast<const uint2v*>(
            qbase + (size_t)((unsigned)idxs[t] * 128u));
        acc0[0] += __builtin_amdgcn_cvt_pk_f32_fp8(d.x, false);
        acc0[1] += __builtin_amdgcn_cvt_pk_f32_fp8(d.x, true);
        acc0[2] += __builtin_amdgcn_cvt_pk_f32_fp8(d.y, false);
        acc0[3] += __builtin_amdgcn_cvt_pk_f32_fp8(d.y, true);
    }
#pragma unroll
    for (int t = 8; t < 16; ++t) {
        uint2v d = *reinterpret_cast<const uint2v*>(
            qbase + (size_t)((unsigned)idxs[t] * 128u));
        acc1[0] += __builtin_amdgcn_cvt_pk_f32_fp8(d.x, false);
        acc1[1] += __builtin_amdgcn_cvt_pk_f32_fp8(d.x, true);
        acc1[2] += __builtin_amdgcn_cvt_pk_f32_fp8(d.y, false);
        acc1[3] += __builtin_amdgcn_cvt_pk_f32_fp8(d.y, true);
    }
#pragma unroll
    for (int t = 16; t < 24; ++t) {
        uint2v d = *reinterpret_cast<const uint2v*>(
            qbase + (size_t)((unsigned)idxs[t] * 128u));
        acc2[0] += __builtin_amdgcn_cvt_pk_f32_fp8(d.x, false);
        acc2[1] += __builtin_amdgcn_cvt_pk_f32_fp8(d.x, true);
        acc2[2] += __builtin_amdgcn_cvt_pk_f32_fp8(d.y, false);
        acc2[3] += __builtin_amdgcn_cvt_pk_f32_fp8(d.y, true);
    }
#pragma unroll
    for (int mm = 16; mm <= 32; mm <<= 1) {
#pragma unroll
        for (int q = 0; q < 4; ++q) {
            acc0[q] += shfl_xor_f2(acc0[q], mm);
            acc1[q] += shfl_xor_f2(acc1[q], mm);
            acc2[q] += shfl_xor_f2(acc2[q], mm);
        }
    }
    const float inv = 1.f / 32.f;
    float p0 = 0.f, p1 = 0.f;
    if (g == 0) {
        // inter2 for features f=8e..8e+7; self i1 row from fp8
        float sarr[8];
        {
            uint2v sd = *reinterpret_cast<const uint2v*>(
                qbase + (size_t)((unsigned)n * 128u));
            f32x2 s0 = __builtin_amdgcn_cvt_pk_f32_fp8(sd.x, false);
            f32x2 s1 = __builtin_amdgcn_cvt_pk_f32_fp8(sd.x, true);
            f32x2 s2 = __builtin_amdgcn_cvt_pk_f32_fp8(sd.y, false);
            f32x2 s3 = __builtin_amdgcn_cvt_pk_f32_fp8(sd.y, true);
            sarr[0] = s0.x; sarr[1] = s0.y; sarr[2] = s1.x; sarr[3] = s1.y;
            sarr[4] = s2.x; sarr[5] = s2.y; sarr[6] = s3.x; sarr[7] = s3.y;
        }
        const float* wa = swl + 24 * e;
        const float* wb = swl + 384 + 24 * e;
#pragma unroll
        for (int i = 0; i < 8; ++i) {
            int f = 8 * e + i;
            float a0 = acc0[i >> 1][i & 1] * inv;
            float a1 = acc1[i >> 1][i & 1] * inv;
            float a2 = acc2[i >> 1][i & 1] * inv;
            float s = sarr[i];
            float i2a = wa[3 * i] * a0 + wa[3 * i + 1] * a1 + wa[3 * i + 2] * a2;
            float i2b = wb[3 * i] * (s - a0) + wb[3 * i + 1] * (s - a1) +
                        wb[3 * i + 2] * (s - a2);
            p0 += i2a * w_d2[(192 + f) * 2 + 0] + i2b * w_d2[(320 + f) * 2 + 0];
            p1 += i2a * w_d2[(192 + f) * 2 + 1] + i2b * w_d2[(320 + f) * 2 + 1];
        }
    } else if (g == 1) {
        // self h0 features 4e..4e+3 from fp8
        unsigned d = *reinterpret_cast<const unsigned*>(h0q + (size_t)n * 64 + 4 * e);
        f32x2 lo = __builtin_amdgcn_cvt_pk_f32_fp8(d, false);
        f32x2 hi = __builtin_amdgcn_cvt_pk_f32_fp8(d, true);
        float sv[4] = {lo.x, lo.y, hi.x, hi.y};
#pragma unroll
        for (int i = 0; i < 4; ++i) {
            int f = 4 * e + i;
            p0 += sv[i] * w_d2[f * 2 + 0];
            p1 += sv[i] * w_d2[f * 2 + 1];
        }
    } else if (g == 2) {
        // self inter1 features 8e..8e+7 from fp8 -> w_d2 rows 64+f
        float sarr[8];
        {
            uint2v sd = *reinterpret_cast<const uint2v*>(
                qbase + (size_t)((unsigned)n * 128u));
            f32x2 s0 = __builtin_amdgcn_cvt_pk_f32_fp8(sd.x, false);
            f32x2 s1 = __builtin_amdgcn_cvt_pk_f32_fp8(sd.x, true);
            f32x2 s2 = __builtin_amdgcn_cvt_pk_f32_fp8(sd.y, false);
            f32x2 s3 = __builtin_amdgcn_cvt_pk_f32_fp8(sd.y, true);
            sarr[0] = s0.x; sarr[1] = s0.y; sarr[2] = s1.x; sarr[3] = s1.y;
            sarr[4] = s2.x; sarr[5] = s2.y; sarr[6] = s3.x; sarr[7] = s3.y;
        }
#pragma unroll
        for (int i = 0; i < 8; ++i) {
            int f = 8 * e + i;
            p0 += sarr[i] * w_d2[(64 + f) * 2 + 0];
            p1 += sarr[i] * w_d2[(64 + f) * 2 + 1];
        }
    }
#pragma unroll
    for (int mm = 1; mm <= 32; mm <<= 1) {
        p0 += __shfl_xor(p0, mm, 64);
        p1 += __shfl_xor(p1, mm, 64);
    }
    if (j == 0) {
        float x0 = p0 + b_d2[0], x1 = p1 + b_d2[1];
        x0 = x0 > 0.f ? x0 : 0.3f * x0;
        x1 = x1 > 0.f ? x1 : 0.3f * x1;
        x0 += __logf(prior[0]);
        x1 += __logf(prior[1]);
        float z = x0 * w_d1[0] + x1 * w_d1[1] + b_d1[0];
        out[bb] = 1.f / (1.f + __expf(-z));
    }
}

extern "C" void kernel_launch(void* const* d_in, const int* in_sizes, int n_in,
                              void* d_out, int out_size, void* d_ws, size_t ws_size,
                              hipStream_t stream) {
    const int*   nodes  = (const int*)d_in[0];
    const float* feat   = (const float*)d_in[1];
    const int*   adj    = (const int*)d_in[2];
    const float* prior  = (const float*)d_in[3];
    const float* w_mlp  = (const float*)d_in[4];
    const float* b_mlp  = (const float*)d_in[5];
    const float* alpha1 = (const float*)d_in[6];
    const float* alpha2 = (const float*)d_in[7];
    const float* w_d2   = (const float*)d_in[8];
    const float* b_d2   = (const float*)d_in[9];
    const float* w_d1   = (const float*)d_in[10];
    const float* b_d1   = (const float*)d_in[11];
    float* out = (float*)d_out;

    // ws: sw1(384f) | sw2(768f) | pad->8192 | h0q fp8 N*64 (3.2MB) |
    //     i1q fp8 N*128 (6.4MB)
    float* sw1 = (float*)d_ws;
    float* sw2 = sw1 + 128 * 3;
    unsigned char* h0q = (unsigned char*)((char*)d_ws + 8192);
    unsigned char* i1q = h0q + (size_t)N_NODES * 64;

    mlp_kernel<<<2048, 256, 0, stream>>>(feat, w_mlp, b_mlp, alpha1, alpha2,
                                         sw1, sw2, h0q);
    layer1_kernel<<<N_NODES / 16, 128, 0, stream>>>(adj, h0q, sw1, i1q);
    layer2_kernel<<<BATCH / 4, 256, 0, stream>>>(nodes, adj, h0q, i1q, sw2,
                                                 w_d2, b_d2, w_d1, b_d1, prior, out);
}